// Round 1
// baseline (307.171 us; speedup 1.0000x reference)
//
#include <hip/hip_runtime.h>
#include <hip/hip_fp16.h>

#define NB 2049
#define TF 600
#define WINF 300
#define NFFT 4096
#define HOP 1024
#define ALEN 613376
#define EPSV 1e-10f
#define SQEPS 1e-5f

__device__ __forceinline__ float2 cmul(float2 a, float2 b) {
  return make_float2(a.x*b.x - a.y*b.y, a.x*b.y + a.y*b.x);
}

__global__ __launch_bounds__(256) void k_init(unsigned int* c2max) {
  if (blockIdx.x == 0 && threadIdx.x < 4) c2max[threadIdx.x] = 0u;
}

// ---- K1: per-window max |mix|^2 -------------------------------------------
__global__ __launch_bounds__(256) void k_maxred(const float* __restrict__ mix,
                                                unsigned int* __restrict__ c2max) {
  int winid = blockIdx.x >> 6;
  int blk = blockIdx.x & 63;
  const float4* p = (const float4*)(mix + (size_t)winid * (WINF * NB * 2 * 2));
  const int n4 = WINF * NB * 2 * 2 / 4;  // 614700
  float m = 0.f;
  for (int i = blk * 256 + threadIdx.x; i < n4; i += 64 * 256) {
    float4 v = p[i];
    m = fmaxf(m, fmaxf(v.x*v.x + v.y*v.y, v.z*v.z + v.w*v.w));
  }
  for (int off = 32; off; off >>= 1) m = fmaxf(m, __shfl_xor(m, off));
  __shared__ float sm[4];
  if ((threadIdx.x & 63) == 0) sm[threadIdx.x >> 6] = m;
  __syncthreads();
  if (threadIdx.x == 0) {
    m = fmaxf(fmaxf(sm[0], sm[1]), fmaxf(sm[2], sm[3]));
    atomicMax(c2max + winid, __float_as_uint(m));
  }
}

// ---- K2: covariance R per (window, f, s) ----------------------------------
// Rbuf[win][f][s][4] = {R00, R11, Re R01, Im R01}
__global__ __launch_bounds__(256) void k_rmat(const float* __restrict__ spec,
                                              const float* __restrict__ mix,
                                              const unsigned int* __restrict__ c2max,
                                              float* __restrict__ Rbuf) {
  int f = blockIdx.x;
  int winid = threadIdx.x >> 6;
  int lane = threadIdx.x & 63;
  int b = winid >> 1, w = winid & 1;
  float acc[16];
#pragma unroll
  for (int i = 0; i < 16; i++) acc[i] = 0.f;
  for (int tl = lane; tl < WINF; tl += 64) {
    int t = w * WINF + tl;
    size_t base = (size_t)(b * TF + t) * NB + f;
    const float4* sp = (const float4*)(spec + base * 8);
    float4 s0 = sp[0], s1 = sp[1];
    float4 mx = *(const float4*)(mix + base * 4);
    float n0 = mx.x*mx.x + mx.y*mx.y;
    float n1 = mx.z*mx.z + mx.w*mx.w;
    float qr, qi;  // q = p0 * conj(p1), p_a = unit phase of mix_a (1 if zero)
    if (n0 > 0.f && n1 > 0.f) {
      float inv = rsqrtf(n0 * n1);
      qr = (mx.x*mx.z + mx.y*mx.w) * inv;
      qi = (mx.y*mx.z - mx.x*mx.w) * inv;
    } else if (n0 > 0.f) { float inv = rsqrtf(n0); qr = mx.x*inv; qi = mx.y*inv; }
    else if (n1 > 0.f)   { float inv = rsqrtf(n1); qr = mx.z*inv; qi = -mx.w*inv; }
    else { qr = 1.f; qi = 0.f; }
    float A0[4] = {s0.x, s0.y, s0.z, s0.w};
    float A1[4] = {s1.x, s1.y, s1.z, s1.w};
#pragma unroll
    for (int s = 0; s < 4; s++) {
      acc[s*4+0] += A0[s]*A0[s];
      acc[s*4+1] += A1[s]*A1[s];
      float aa = A0[s]*A1[s];
      acc[s*4+2] += aa * qr;
      acc[s*4+3] += aa * qi;
    }
  }
#pragma unroll
  for (int i = 0; i < 16; i++) {
#pragma unroll
    for (int off = 32; off; off >>= 1) acc[i] += __shfl_xor(acc[i], off);
  }
  if (lane == 0) {
    float c = fmaxf(1.f, sqrtf(__uint_as_float(c2max[winid])) * 0.1f);
    float c2 = c * c;
#pragma unroll
    for (int s = 0; s < 4; s++) {
      float W = c2 * EPSV + 0.5f * (acc[s*4+0] + acc[s*4+1]);
      float invW = 1.f / W;
      float4 R = make_float4(acc[s*4+0]*invW, acc[s*4+1]*invW,
                             acc[s*4+2]*invW, acc[s*4+3]*invW);
      *(float4*)(Rbuf + ((size_t)winid * NB + f) * 16 + s * 4) = R;
    }
  }
}

// ---- K3: EM apply, write Y (fp16 complex) in [b][s][c][t][f] --------------
__global__ __launch_bounds__(256) void k_apply(const float* __restrict__ spec,
                                               const float* __restrict__ mix,
                                               const unsigned int* __restrict__ c2max,
                                               const float* __restrict__ Rbuf,
                                               __half2* __restrict__ Y) {
  size_t idx = (size_t)blockIdx.x * 256 + threadIdx.x;
  if (idx >= (size_t)2 * TF * NB) return;
  int f = (int)(idx % NB);
  int r = (int)(idx / NB);
  int t = r % TF, b = r / TF;
  int winid = b * 2 + (t >= WINF ? 1 : 0);
  float c = fmaxf(1.f, sqrtf(__uint_as_float(c2max[winid])) * 0.1f);
  float invc = 1.f / c, inv2c2 = 0.5f * invc * invc;
  size_t base = (size_t)(b * TF + t) * NB + f;
  const float4* sp = (const float4*)(spec + base * 8);
  float4 s0v = sp[0], s1v = sp[1];
  float4 mx = *(const float4*)(mix + base * 4);
  const float4* Rp = (const float4*)(Rbuf + ((size_t)winid * NB + f) * 16);
  float A0[4] = {s0v.x, s0v.y, s0v.z, s0v.w};
  float A1[4] = {s1v.x, s1v.y, s1v.z, s1v.w};
  float v[4]; float4 R[4];
  float C00 = SQEPS, C11 = SQEPS, C01r = 0.f, C01i = 0.f;
#pragma unroll
  for (int sq = 0; sq < 4; sq++) {
    R[sq] = Rp[sq];
    v[sq] = (A0[sq]*A0[sq] + A1[sq]*A1[sq]) * inv2c2;
    C00 += v[sq]*R[sq].x; C11 += v[sq]*R[sq].y;
    C01r += v[sq]*R[sq].z; C01i += v[sq]*R[sq].w;
  }
  float det = C00*C11 - (C01r*C01r + C01i*C01i);
  float invdet = 1.f / det;
  float x0r = mx.x*invc, x0i = mx.y*invc, x1r = mx.z*invc, x1i = mx.w*invc;
  float ix0r = (C11*x0r - (C01r*x1r - C01i*x1i)) * invdet;
  float ix0i = (C11*x0i - (C01r*x1i + C01i*x1r)) * invdet;
  float ix1r = (C00*x1r - (C01r*x0r + C01i*x0i)) * invdet;
  float ix1i = (C00*x1i - (C01r*x0i - C01i*x0r)) * invdet;
#pragma unroll
  for (int sq = 0; sq < 4; sq++) {
    float vc = v[sq] * c;
    float y0r = vc*(R[sq].x*ix0r + R[sq].z*ix1r - R[sq].w*ix1i);
    float y0i = vc*(R[sq].x*ix0i + R[sq].z*ix1i + R[sq].w*ix1r);
    float y1r = vc*(R[sq].z*ix0r + R[sq].w*ix0i + R[sq].y*ix1r);
    float y1i = vc*(R[sq].z*ix0i - R[sq].w*ix0r + R[sq].y*ix1i);
    size_t pbase = ((size_t)((b * 4 + sq) * 2) * TF + t) * NB + f;
    Y[pbase] = __floats2half2_rn(y0r, y0i);
    Y[pbase + (size_t)TF * NB] = __floats2half2_rn(y1r, y1i);
  }
}

// EM solve for one (s, ch) output — fused fallback path
__device__ __forceinline__ float2 em_point_one(const float* __restrict__ spec,
    const float* __restrict__ mix, const float* __restrict__ Rbuf,
    const unsigned int* __restrict__ c2max, int b, int t, int f, int ssel, int ch) {
  int winid = b * 2 + (t >= WINF ? 1 : 0);
  float c = fmaxf(1.f, sqrtf(__uint_as_float(c2max[winid])) * 0.1f);
  float invc = 1.f / c, inv2c2 = 0.5f * invc * invc;
  size_t base = (size_t)(b * TF + t) * NB + f;
  const float4* sp = (const float4*)(spec + base * 8);
  float4 s0 = sp[0], s1 = sp[1];
  float4 mx = *(const float4*)(mix + base * 4);
  const float4* Rp = (const float4*)(Rbuf + ((size_t)winid * NB + f) * 16);
  float A0v[4] = {s0.x, s0.y, s0.z, s0.w};
  float A1v[4] = {s1.x, s1.y, s1.z, s1.w};
  float C00 = SQEPS, C11 = SQEPS, C01r = 0.f, C01i = 0.f;
  float vsel = 0.f; float4 Rsel = make_float4(0.f, 0.f, 0.f, 0.f);
#pragma unroll
  for (int sq = 0; sq < 4; sq++) {
    float4 R = Rp[sq];
    float v = (A0v[sq]*A0v[sq] + A1v[sq]*A1v[sq]) * inv2c2;
    C00 += v*R.x; C11 += v*R.y; C01r += v*R.z; C01i += v*R.w;
    if (sq == ssel) { vsel = v; Rsel = R; }
  }
  float det = C00*C11 - (C01r*C01r + C01i*C01i);
  float invdet = 1.f / det;
  float x0r = mx.x*invc, x0i = mx.y*invc, x1r = mx.z*invc, x1i = mx.w*invc;
  float ix0r = (C11*x0r - (C01r*x1r - C01i*x1i)) * invdet;
  float ix0i = (C11*x0i - (C01r*x1i + C01i*x1r)) * invdet;
  float ix1r = (C00*x1r - (C01r*x0r + C01i*x0i)) * invdet;
  float ix1i = (C00*x1i - (C01r*x0i - C01i*x0r)) * invdet;
  float vc = vsel * c;
  if (ch == 0)
    return make_float2(vc*(Rsel.x*ix0r + Rsel.z*ix1r - Rsel.w*ix1i),
                       vc*(Rsel.x*ix0i + Rsel.z*ix1i + Rsel.w*ix1r));
  return make_float2(vc*(Rsel.z*ix0r + Rsel.w*ix0i + Rsel.y*ix1r),
                     vc*(Rsel.z*ix0i - Rsel.w*ix0r + Rsel.y*ix1i));
}

// ---- FFT stages (inverse Stockham, N=2048) --------------------------------
template<int NS>
__device__ __forceinline__ void r4stage(const float2* __restrict__ src,
                                        float2* __restrict__ dst,
                                        const float2* __restrict__ tw, int tid) {
#pragma unroll
  for (int qq = 0; qq < 2; qq++) {
    int q = tid + qq * 256;
    int jm = q & (NS - 1);
    float2 v0 = src[q];
    float2 v1 = src[q + 512];
    float2 v2 = src[q + 1024];
    float2 v3 = src[q + 1536];
    if constexpr (NS > 1) {
      int p = jm * (512 / NS);
      v1 = cmul(v1, tw[p]);
      v2 = cmul(v2, tw[2 * p]);
      v3 = cmul(v3, tw[3 * p]);
    }
    float2 t0 = make_float2(v0.x + v2.x, v0.y + v2.y);
    float2 t1 = make_float2(v0.x - v2.x, v0.y - v2.y);
    float2 t2 = make_float2(v1.x + v3.x, v1.y + v3.y);
    float2 t3 = make_float2(v1.x - v3.x, v1.y - v3.y);
    int d = ((q - jm) << 2) + jm;
    dst[d]          = make_float2(t0.x + t2.x, t0.y + t2.y);
    dst[d + NS]     = make_float2(t1.x - t3.y, t1.y + t3.x);  // t1 + i*t3
    dst[d + 2*NS]   = make_float2(t0.x - t2.x, t0.y - t2.y);
    dst[d + 3*NS]   = make_float2(t1.x + t3.y, t1.y - t3.x);  // t1 - i*t3
  }
}

__device__ __forceinline__ void r2stage(const float2* __restrict__ src,
                                        float2* __restrict__ dst,
                                        const float2* __restrict__ tw, int tid) {
#pragma unroll
  for (int qq = 0; qq < 4; qq++) {
    int q = tid + qq * 256;
    float2 v0 = src[q];
    float2 v1 = cmul(src[q + 1024], tw[q]);
    dst[q]        = make_float2(v0.x + v1.x, v0.y + v1.y);
    dst[q + 1024] = make_float2(v0.x - v1.x, v0.y - v1.y);
  }
}

// ---- K4: ISTFT. One workgroup per (stream, 4096-sample output chunk) ------
template<bool FUSED>
__global__ __launch_bounds__(256) void k_istft(const __half2* __restrict__ Y,
        const float* __restrict__ spec, const float* __restrict__ mix,
        const unsigned int* __restrict__ c2max, const float* __restrict__ Rbuf,
        float* __restrict__ out) {
  __shared__ float2 bufA[2048];
  __shared__ float2 bufB[2048];
  __shared__ float2 tw[1536];
  const int tid = threadIdx.x;
  const int u = blockIdx.x % 150;
  const int sid = blockIdx.x / 150;
  const int b = sid >> 3;
  const int s = (sid >> 1) & 3;
  const int ch = sid & 1;

  for (int p = tid; p < 1536; p += 256) {
    float sn, cs;
    __sincosf((float)p * 0.003067961575771282f /* 2pi/2048 */, &sn, &cs);
    tw[p] = make_float2(cs, sn);
  }
  float acc[16], wsm[16];
#pragma unroll
  for (int k = 0; k < 16; k++) { acc[k] = 0.f; wsm[k] = 0.f; }
  const int t0 = max(0, 4 * u - 1);
  const int t1 = min(TF - 1, 4 * u + 5);
  const int M0 = 2048 + u * 4096;
  __syncthreads();
  for (int t = t0; t <= t1; ++t) {
    // Hermitian fold: Z[k] = Xe + i*Xo -> bufA  (imag of bins 0,2048 dropped)
    for (int k = tid; k < 2048; k += 256) {
      float2 Xa, Xb;
      if constexpr (FUSED) {
        Xa = em_point_one(spec, mix, Rbuf, c2max, b, t, k, s, ch);
        Xb = em_point_one(spec, mix, Rbuf, c2max, b, t, 2048 - k, s, ch);
      } else {
        const __half2* Yrow = Y + ((size_t)sid * TF + t) * NB;
        Xa = __half22float2(Yrow[k]);
        Xb = __half22float2(Yrow[2048 - k]);
      }
      if (k == 0) { Xa.y = 0.f; Xb.y = 0.f; }
      float Sx = Xa.x + Xb.x, Sy = Xa.y - Xb.y;
      float Dx = Xa.x - Xb.x, Dy = Xa.y + Xb.y;
      float sn, cs;
      __sincosf((float)k * 0.0015339807878856412f /* pi/2048 */, &sn, &cs);
      bufA[k] = make_float2(0.5f * (Sx - sn*Dx - cs*Dy),
                            0.5f * (Sy + cs*Dx - sn*Dy));
    }
    __syncthreads();
    r4stage<1>(bufA, bufB, tw, tid);   __syncthreads();
    r4stage<4>(bufB, bufA, tw, tid);   __syncthreads();
    r4stage<16>(bufA, bufB, tw, tid);  __syncthreads();
    r4stage<64>(bufB, bufA, tw, tid);  __syncthreads();
    r4stage<256>(bufA, bufB, tw, tid); __syncthreads();
    r2stage(bufB, bufA, tw, tid);      __syncthreads();
    // accumulate windowed samples + analytic wsum
    const int delta = M0 - t * HOP;
#pragma unroll
    for (int k2 = 0; k2 < 16; k2++) {
      int n = tid + 256 * k2 + delta;
      if (n >= 0 && n < NFFT) {
        float2 z = bufA[n >> 1];
        float xn = (n & 1) ? z.y : z.x;
        float wn = 0.5f - 0.5f * __cosf((float)n * 0.0015339807878856412f /* 2pi/4096 */);
        acc[k2] += xn * wn * (1.f / 2048.f);
        wsm[k2] += wn * wn;
      }
    }
    __syncthreads();
  }
#pragma unroll
  for (int k2 = 0; k2 < 16; k2++) {
    size_t o = (size_t)u * 4096 + tid + 256 * k2;
    if (o < (size_t)ALEN) {
      float wsv = wsm[k2];
      out[(size_t)sid * ALEN + o] = acc[k2] / (wsv > 1e-11f ? wsv : 1.f);
    }
  }
}

extern "C" void kernel_launch(void* const* d_in, const int* in_sizes, int n_in,
                              void* d_out, int out_size, void* d_ws, size_t ws_size,
                              hipStream_t stream) {
  const float* spec = (const float*)d_in[0];
  const float* mix  = (const float*)d_in[1];
  float* out = (float*)d_out;
  unsigned char* ws = (unsigned char*)d_ws;
  unsigned int* c2max = (unsigned int*)ws;         // 16 B
  float* Rbuf = (float*)(ws + 256);                // 4*2049*16*4 = 524544 B
  __half2* Y = (__half2*)(ws + 524800);            // 16*600*2049*4 B = 78.7 MB
  const size_t needY = 524800 + (size_t)16 * TF * NB * 4;

  k_init<<<1, 256, 0, stream>>>(c2max);
  k_maxred<<<256, 256, 0, stream>>>(mix, c2max);
  k_rmat<<<NB, 256, 0, stream>>>(spec, mix, c2max, Rbuf);
  if (ws_size >= needY) {
    int total = 2 * TF * NB;
    k_apply<<<(total + 255) / 256, 256, 0, stream>>>(spec, mix, c2max, Rbuf, Y);
    k_istft<false><<<16 * 150, 256, 0, stream>>>(Y, spec, mix, c2max, Rbuf, out);
  } else {
    k_istft<true><<<16 * 150, 256, 0, stream>>>(nullptr, spec, mix, c2max, Rbuf, out);
  }
}

// Round 2
// 295.683 us; speedup vs baseline: 1.0389x; 1.0389x over previous
//
#include <hip/hip_runtime.h>
#include <hip/hip_fp16.h>

#define NB 2049
#define TF 600
#define WINF 300
#define NFFT 4096
#define HOP 1024
#define ALEN 613376
#define EPSV 1e-10f
#define SQEPS 1e-5f

// LDS padding: i + (i>>4) gives exactly-floor bank distribution (4 lanes/bank
// for b64) for every access pattern in the Stockham pipeline. 2048 -> 2176.
#define PADI(i) ((i) + ((i) >> 4))

__device__ __forceinline__ float2 cmul(float2 a, float2 b) {
  return make_float2(a.x*b.x - a.y*b.y, a.x*b.y + a.y*b.x);
}

__global__ __launch_bounds__(256) void k_init(unsigned int* c2max) {
  if (blockIdx.x == 0 && threadIdx.x < 4) c2max[threadIdx.x] = 0u;
}

// ---- K1: per-window max |mix|^2 -------------------------------------------
__global__ __launch_bounds__(256) void k_maxred(const float* __restrict__ mix,
                                                unsigned int* __restrict__ c2max) {
  int winid = blockIdx.x >> 6;
  int blk = blockIdx.x & 63;
  const float4* p = (const float4*)(mix + (size_t)winid * (WINF * NB * 2 * 2));
  const int n4 = WINF * NB * 2 * 2 / 4;  // 614700
  float m = 0.f;
  for (int i = blk * 256 + threadIdx.x; i < n4; i += 64 * 256) {
    float4 v = p[i];
    m = fmaxf(m, fmaxf(v.x*v.x + v.y*v.y, v.z*v.z + v.w*v.w));
  }
  for (int off = 32; off; off >>= 1) m = fmaxf(m, __shfl_xor(m, off));
  __shared__ float sm[4];
  if ((threadIdx.x & 63) == 0) sm[threadIdx.x >> 6] = m;
  __syncthreads();
  if (threadIdx.x == 0) {
    m = fmaxf(fmaxf(sm[0], sm[1]), fmaxf(sm[2], sm[3]));
    atomicMax(c2max + winid, __float_as_uint(m));
  }
}

// ---- K2: covariance R per (window, f, s) ----------------------------------
// Rbuf[win][f][s][4] = {R00, R11, Re R01, Im R01}
__global__ __launch_bounds__(256) void k_rmat(const float* __restrict__ spec,
                                              const float* __restrict__ mix,
                                              const unsigned int* __restrict__ c2max,
                                              float* __restrict__ Rbuf) {
  int f = blockIdx.x;
  int winid = threadIdx.x >> 6;
  int lane = threadIdx.x & 63;
  int b = winid >> 1, w = winid & 1;
  float acc[16];
#pragma unroll
  for (int i = 0; i < 16; i++) acc[i] = 0.f;
  for (int tl = lane; tl < WINF; tl += 64) {
    int t = w * WINF + tl;
    size_t base = (size_t)(b * TF + t) * NB + f;
    const float4* sp = (const float4*)(spec + base * 8);
    float4 s0 = sp[0], s1 = sp[1];
    float4 mx = *(const float4*)(mix + base * 4);
    float n0 = mx.x*mx.x + mx.y*mx.y;
    float n1 = mx.z*mx.z + mx.w*mx.w;
    float qr, qi;  // q = p0 * conj(p1), p_a = unit phase of mix_a (1 if zero)
    if (n0 > 0.f && n1 > 0.f) {
      float inv = rsqrtf(n0 * n1);
      qr = (mx.x*mx.z + mx.y*mx.w) * inv;
      qi = (mx.y*mx.z - mx.x*mx.w) * inv;
    } else if (n0 > 0.f) { float inv = rsqrtf(n0); qr = mx.x*inv; qi = mx.y*inv; }
    else if (n1 > 0.f)   { float inv = rsqrtf(n1); qr = mx.z*inv; qi = -mx.w*inv; }
    else { qr = 1.f; qi = 0.f; }
    float A0[4] = {s0.x, s0.y, s0.z, s0.w};
    float A1[4] = {s1.x, s1.y, s1.z, s1.w};
#pragma unroll
    for (int s = 0; s < 4; s++) {
      acc[s*4+0] += A0[s]*A0[s];
      acc[s*4+1] += A1[s]*A1[s];
      float aa = A0[s]*A1[s];
      acc[s*4+2] += aa * qr;
      acc[s*4+3] += aa * qi;
    }
  }
#pragma unroll
  for (int i = 0; i < 16; i++) {
#pragma unroll
    for (int off = 32; off; off >>= 1) acc[i] += __shfl_xor(acc[i], off);
  }
  if (lane == 0) {
    float c = fmaxf(1.f, sqrtf(__uint_as_float(c2max[winid])) * 0.1f);
    float c2 = c * c;
#pragma unroll
    for (int s = 0; s < 4; s++) {
      float W = c2 * EPSV + 0.5f * (acc[s*4+0] + acc[s*4+1]);
      float invW = 1.f / W;
      float4 R = make_float4(acc[s*4+0]*invW, acc[s*4+1]*invW,
                             acc[s*4+2]*invW, acc[s*4+3]*invW);
      *(float4*)(Rbuf + ((size_t)winid * NB + f) * 16 + s * 4) = R;
    }
  }
}

// ---- K3: EM apply, write Y (fp16 complex) in [b][s][c][t][f] --------------
__global__ __launch_bounds__(256) void k_apply(const float* __restrict__ spec,
                                               const float* __restrict__ mix,
                                               const unsigned int* __restrict__ c2max,
                                               const float* __restrict__ Rbuf,
                                               __half2* __restrict__ Y) {
  size_t idx = (size_t)blockIdx.x * 256 + threadIdx.x;
  if (idx >= (size_t)2 * TF * NB) return;
  int f = (int)(idx % NB);
  int r = (int)(idx / NB);
  int t = r % TF, b = r / TF;
  int winid = b * 2 + (t >= WINF ? 1 : 0);
  float c = fmaxf(1.f, sqrtf(__uint_as_float(c2max[winid])) * 0.1f);
  float invc = 1.f / c, inv2c2 = 0.5f * invc * invc;
  size_t base = (size_t)(b * TF + t) * NB + f;
  const float4* sp = (const float4*)(spec + base * 8);
  float4 s0v = sp[0], s1v = sp[1];
  float4 mx = *(const float4*)(mix + base * 4);
  const float4* Rp = (const float4*)(Rbuf + ((size_t)winid * NB + f) * 16);
  float A0[4] = {s0v.x, s0v.y, s0v.z, s0v.w};
  float A1[4] = {s1v.x, s1v.y, s1v.z, s1v.w};
  float v[4]; float4 R[4];
  float C00 = SQEPS, C11 = SQEPS, C01r = 0.f, C01i = 0.f;
#pragma unroll
  for (int sq = 0; sq < 4; sq++) {
    R[sq] = Rp[sq];
    v[sq] = (A0[sq]*A0[sq] + A1[sq]*A1[sq]) * inv2c2;
    C00 += v[sq]*R[sq].x; C11 += v[sq]*R[sq].y;
    C01r += v[sq]*R[sq].z; C01i += v[sq]*R[sq].w;
  }
  float det = C00*C11 - (C01r*C01r + C01i*C01i);
  float invdet = 1.f / det;
  float x0r = mx.x*invc, x0i = mx.y*invc, x1r = mx.z*invc, x1i = mx.w*invc;
  float ix0r = (C11*x0r - (C01r*x1r - C01i*x1i)) * invdet;
  float ix0i = (C11*x0i - (C01r*x1i + C01i*x1r)) * invdet;
  float ix1r = (C00*x1r - (C01r*x0r + C01i*x0i)) * invdet;
  float ix1i = (C00*x1i - (C01r*x0i - C01i*x0r)) * invdet;
#pragma unroll
  for (int sq = 0; sq < 4; sq++) {
    float vc = v[sq] * c;
    float y0r = vc*(R[sq].x*ix0r + R[sq].z*ix1r - R[sq].w*ix1i);
    float y0i = vc*(R[sq].x*ix0i + R[sq].z*ix1i + R[sq].w*ix1r);
    float y1r = vc*(R[sq].z*ix0r + R[sq].w*ix0i + R[sq].y*ix1r);
    float y1i = vc*(R[sq].z*ix0i - R[sq].w*ix0r + R[sq].y*ix1i);
    size_t pbase = ((size_t)((b * 4 + sq) * 2) * TF + t) * NB + f;
    Y[pbase] = __floats2half2_rn(y0r, y0i);
    Y[pbase + (size_t)TF * NB] = __floats2half2_rn(y1r, y1i);
  }
}

// EM solve for one (s, ch) output — fused fallback path
__device__ __forceinline__ float2 em_point_one(const float* __restrict__ spec,
    const float* __restrict__ mix, const float* __restrict__ Rbuf,
    const unsigned int* __restrict__ c2max, int b, int t, int f, int ssel, int ch) {
  int winid = b * 2 + (t >= WINF ? 1 : 0);
  float c = fmaxf(1.f, sqrtf(__uint_as_float(c2max[winid])) * 0.1f);
  float invc = 1.f / c, inv2c2 = 0.5f * invc * invc;
  size_t base = (size_t)(b * TF + t) * NB + f;
  const float4* sp = (const float4*)(spec + base * 8);
  float4 s0 = sp[0], s1 = sp[1];
  float4 mx = *(const float4*)(mix + base * 4);
  const float4* Rp = (const float4*)(Rbuf + ((size_t)winid * NB + f) * 16);
  float A0v[4] = {s0.x, s0.y, s0.z, s0.w};
  float A1v[4] = {s1.x, s1.y, s1.z, s1.w};
  float C00 = SQEPS, C11 = SQEPS, C01r = 0.f, C01i = 0.f;
  float vsel = 0.f; float4 Rsel = make_float4(0.f, 0.f, 0.f, 0.f);
#pragma unroll
  for (int sq = 0; sq < 4; sq++) {
    float4 R = Rp[sq];
    float v = (A0v[sq]*A0v[sq] + A1v[sq]*A1v[sq]) * inv2c2;
    C00 += v*R.x; C11 += v*R.y; C01r += v*R.z; C01i += v*R.w;
    if (sq == ssel) { vsel = v; Rsel = R; }
  }
  float det = C00*C11 - (C01r*C01r + C01i*C01i);
  float invdet = 1.f / det;
  float x0r = mx.x*invc, x0i = mx.y*invc, x1r = mx.z*invc, x1i = mx.w*invc;
  float ix0r = (C11*x0r - (C01r*x1r - C01i*x1i)) * invdet;
  float ix0i = (C11*x0i - (C01r*x1i + C01i*x1r)) * invdet;
  float ix1r = (C00*x1r - (C01r*x0r + C01i*x0i)) * invdet;
  float ix1i = (C00*x1i - (C01r*x0i - C01i*x0r)) * invdet;
  float vc = vsel * c;
  if (ch == 0)
    return make_float2(vc*(Rsel.x*ix0r + Rsel.z*ix1r - Rsel.w*ix1i),
                       vc*(Rsel.x*ix0i + Rsel.z*ix1i + Rsel.w*ix1r));
  return make_float2(vc*(Rsel.z*ix0r + Rsel.w*ix0i + Rsel.y*ix1r),
                     vc*(Rsel.z*ix0i - Rsel.w*ix0r + Rsel.y*ix1i));
}

// ---- FFT stages (inverse Stockham, N=2048), twiddles via __sincosf --------
template<int NS>
__device__ __forceinline__ void r4stage(const float2* __restrict__ src,
                                        float2* __restrict__ dst, int tid) {
#pragma unroll
  for (int qq = 0; qq < 2; qq++) {
    int q = tid + qq * 256;
    int jm = q & (NS - 1);
    float2 v0 = src[PADI(q)];
    float2 v1 = src[PADI(q + 512)];
    float2 v2 = src[PADI(q + 1024)];
    float2 v3 = src[PADI(q + 1536)];
    if constexpr (NS > 1) {
      // w1 = e^{+i * jm * pi/(2*NS)}; w2 = w1^2; w3 = w1^3
      float sn, cs;
      __sincosf((float)jm * (1.5707963267948966f / (float)NS), &sn, &cs);
      float2 w1 = make_float2(cs, sn);
      float2 w2 = cmul(w1, w1);
      float2 w3 = cmul(w2, w1);
      v1 = cmul(v1, w1);
      v2 = cmul(v2, w2);
      v3 = cmul(v3, w3);
    }
    float2 t0 = make_float2(v0.x + v2.x, v0.y + v2.y);
    float2 t1 = make_float2(v0.x - v2.x, v0.y - v2.y);
    float2 t2 = make_float2(v1.x + v3.x, v1.y + v3.y);
    float2 t3 = make_float2(v1.x - v3.x, v1.y - v3.y);
    int d = ((q - jm) << 2) + jm;
    dst[PADI(d)]        = make_float2(t0.x + t2.x, t0.y + t2.y);
    dst[PADI(d + NS)]   = make_float2(t1.x - t3.y, t1.y + t3.x);  // t1 + i*t3
    dst[PADI(d + 2*NS)] = make_float2(t0.x - t2.x, t0.y - t2.y);
    dst[PADI(d + 3*NS)] = make_float2(t1.x + t3.y, t1.y - t3.x);  // t1 - i*t3
  }
}

__device__ __forceinline__ void r2stage(const float2* __restrict__ src,
                                        float2* __restrict__ dst, int tid) {
#pragma unroll
  for (int qq = 0; qq < 4; qq++) {
    int q = tid + qq * 256;
    float sn, cs;
    __sincosf((float)q * 0.003067961575771282f /* 2pi/2048 */, &sn, &cs);
    float2 v0 = src[PADI(q)];
    float2 v1 = cmul(src[PADI(q + 1024)], make_float2(cs, sn));
    dst[PADI(q)]        = make_float2(v0.x + v1.x, v0.y + v1.y);
    dst[PADI(q + 1024)] = make_float2(v0.x - v1.x, v0.y - v1.y);
  }
}

// ---- K4: ISTFT. One workgroup per (stream, 4096-sample output chunk) ------
template<bool FUSED>
__global__ __launch_bounds__(256) void k_istft(const __half2* __restrict__ Y,
        const float* __restrict__ spec, const float* __restrict__ mix,
        const unsigned int* __restrict__ c2max, const float* __restrict__ Rbuf,
        float* __restrict__ out) {
  __shared__ float2 bufA[2176];
  __shared__ float2 bufB[2176];
  const int tid = threadIdx.x;
  const int u = blockIdx.x % 150;
  const int sid = blockIdx.x / 150;
  const int b = sid >> 3;
  const int s = (sid >> 1) & 3;
  const int ch = sid & 1;

  float acc[16], wsm[16];
#pragma unroll
  for (int k = 0; k < 16; k++) { acc[k] = 0.f; wsm[k] = 0.f; }
  const int t0 = max(0, 4 * u - 1);
  const int t1 = min(TF - 1, 4 * u + 5);
  const int M0 = 2048 + u * 4096;
  for (int t = t0; t <= t1; ++t) {
    // Hermitian fold: Z[k] = Xe + i*Xo -> bufA  (imag of bins 0,2048 dropped)
    for (int k = tid; k < 2048; k += 256) {
      float2 Xa, Xb;
      if constexpr (FUSED) {
        Xa = em_point_one(spec, mix, Rbuf, c2max, b, t, k, s, ch);
        Xb = em_point_one(spec, mix, Rbuf, c2max, b, t, 2048 - k, s, ch);
      } else {
        const __half2* Yrow = Y + ((size_t)sid * TF + t) * NB;
        Xa = __half22float2(Yrow[k]);
        Xb = __half22float2(Yrow[2048 - k]);
      }
      if (k == 0) { Xa.y = 0.f; Xb.y = 0.f; }
      float Sx = Xa.x + Xb.x, Sy = Xa.y - Xb.y;
      float Dx = Xa.x - Xb.x, Dy = Xa.y + Xb.y;
      float sn, cs;
      __sincosf((float)k * 0.0015339807878856412f /* pi/2048 */, &sn, &cs);
      bufA[PADI(k)] = make_float2(0.5f * (Sx - sn*Dx - cs*Dy),
                                  0.5f * (Sy + cs*Dx - sn*Dy));
    }
    __syncthreads();
    r4stage<1>(bufA, bufB, tid);   __syncthreads();
    r4stage<4>(bufB, bufA, tid);   __syncthreads();
    r4stage<16>(bufA, bufB, tid);  __syncthreads();
    r4stage<64>(bufB, bufA, tid);  __syncthreads();
    r4stage<256>(bufA, bufB, tid); __syncthreads();
    r2stage(bufB, bufA, tid);      __syncthreads();
    // accumulate windowed samples + analytic wsum
    const int delta = M0 - t * HOP;
#pragma unroll
    for (int k2 = 0; k2 < 16; k2++) {
      int n = tid + 256 * k2 + delta;
      if (n >= 0 && n < NFFT) {
        float2 z = bufA[PADI(n >> 1)];
        float xn = (n & 1) ? z.y : z.x;
        float wn = 0.5f - 0.5f * __cosf((float)n * 0.0015339807878856412f /* 2pi/4096 */);
        acc[k2] += xn * wn * (1.f / 2048.f);
        wsm[k2] += wn * wn;
      }
    }
    __syncthreads();
  }
#pragma unroll
  for (int k2 = 0; k2 < 16; k2++) {
    size_t o = (size_t)u * 4096 + tid + 256 * k2;
    if (o < (size_t)ALEN) {
      float wsv = wsm[k2];
      out[(size_t)sid * ALEN + o] = acc[k2] / (wsv > 1e-11f ? wsv : 1.f);
    }
  }
}

extern "C" void kernel_launch(void* const* d_in, const int* in_sizes, int n_in,
                              void* d_out, int out_size, void* d_ws, size_t ws_size,
                              hipStream_t stream) {
  const float* spec = (const float*)d_in[0];
  const float* mix  = (const float*)d_in[1];
  float* out = (float*)d_out;
  unsigned char* ws = (unsigned char*)d_ws;
  unsigned int* c2max = (unsigned int*)ws;         // 16 B
  float* Rbuf = (float*)(ws + 256);                // 4*2049*16*4 = 524544 B
  __half2* Y = (__half2*)(ws + 524800);            // 16*600*2049*4 B = 78.7 MB
  const size_t needY = 524800 + (size_t)16 * TF * NB * 4;

  k_init<<<1, 256, 0, stream>>>(c2max);
  k_maxred<<<256, 256, 0, stream>>>(mix, c2max);
  k_rmat<<<NB, 256, 0, stream>>>(spec, mix, c2max, Rbuf);
  if (ws_size >= needY) {
    int total = 2 * TF * NB;
    k_apply<<<(total + 255) / 256, 256, 0, stream>>>(spec, mix, c2max, Rbuf, Y);
    k_istft<false><<<16 * 150, 256, 0, stream>>>(Y, spec, mix, c2max, Rbuf, out);
  } else {
    k_istft<true><<<16 * 150, 256, 0, stream>>>(nullptr, spec, mix, c2max, Rbuf, out);
  }
}